// Round 4
// baseline (348.050 us; speedup 1.0000x reference)
//
#include <hip/hip_runtime.h>
#include <hip/hip_bf16.h>

#define FEAT    512
#define HEADS   4
#define NEG     0.2f

typedef unsigned int uint;
typedef unsigned short ushort_t;
typedef __attribute__((ext_vector_type(8))) short bf16x8v;   // 8 bf16 = 4 VGPRs
typedef __attribute__((ext_vector_type(4))) float f32x4v;    // mfma acc
typedef __attribute__((ext_vector_type(4))) uint uint4v;     // nt-load-able 16B
typedef __attribute__((address_space(3))) uint lds_u32_t;
typedef __attribute__((address_space(1))) const uint g_u32_t;

__device__ inline float bf2f(ushort_t h) { return __uint_as_float(((uint)h) << 16); }
__device__ inline ushort_t f2bf(float f) {
    uint u = __float_as_uint(f);
    u += 0x7fff + ((u >> 16) & 1);           // RNE
    return (ushort_t)(u >> 16);
}
__device__ inline float2 up2(uint d) {       // 2 packed bf16 -> float2, 2 inst
    return make_float2(__uint_as_float(d << 16), __uint_as_float(d & 0xffff0000u));
}
__device__ inline float2 f2add(float2 a, float2 b) { return make_float2(a.x + b.x, a.y + b.y); }
__device__ inline float2 f2min0(float2 a) { return make_float2(fminf(a.x, 0.f), fminf(a.y, 0.f)); }
__device__ inline float2 f2fma(float2 a, float2 b, float2 c) {
    return make_float2(fmaf(a.x, b.x, c.x), fmaf(a.y, b.y, c.y));
}
__device__ inline float2 f2fmas(float s, float2 b, float2 c) {
    return make_float2(fmaf(s, b.x, c.x), fmaf(s, b.y, c.y));
}

// ---------------------------------------------------------------------------
// fused prep: dtype probe (per-block, from the same 256B of x -> no cross-block
// dep), deg zeroing, small-array canon, and x canon. 1 dispatch replaces 4.
// block roles: [0,NBZ) zero deg | [NBZ,NBZ+15) canon small4 | rest canon x.
// ---------------------------------------------------------------------------
__global__ __launch_bounds__(256) void prep_kernel(
    const ushort_t* __restrict__ xprobe, int* flag,
    int* __restrict__ deg, int N, int NBZ,
    const void* a0, ushort_t* o0, int n0, const void* a1, ushort_t* o1, int n1,
    const void* a2, ushort_t* o2, int n2, const void* a3, ushort_t* o3, int n3,
    const void* __restrict__ xin, ushort_t* __restrict__ xc, long long nx) {
    __shared__ int s_isbf;
    int tid = threadIdx.x;
    if (tid < 64) {
        int hits = 0;
        for (int i = tid; i < 128; i += 64) {
            ushort_t w = xprobe[2 * i];
            uint hb = (w >> 8) & 0x7f;
            hits += (hb >= 0x38 && hb <= 0x42) ? 1 : 0;
        }
        #pragma unroll
        for (int off = 32; off >= 1; off >>= 1) hits += __shfl_xor(hits, off);
        if (tid == 0) s_isbf = (hits >= 64) ? 1 : 0;
    }
    __syncthreads();
    int isbf = s_isbf;
    int b = blockIdx.x;
    if (b == 0 && tid == 0) *flag = isbf;

    if (b < NBZ) {                       // zero deg (int4)
        int i0 = (b * 256 + tid) * 4;
        if (i0 + 4 <= N) *(int4*)&deg[i0] = make_int4(0, 0, 0, 0);
        else for (int j = 0; j < 4; ++j) if (i0 + j < N) deg[i0 + j] = 0;
        return;
    }
    if (b < NBZ + 15) {                  // canon small4
        int idx = (b - NBZ) * 256 + tid;
        const void* srcs[4] = {a0, a1, a2, a3};
        ushort_t* dsts[4] = {o0, o1, o2, o3};
        int ns[4] = {n0, n1, n2, n3};
        #pragma unroll
        for (int k = 0; k < 4; ++k) {
            if (idx < ns[k]) {
                dsts[k][idx] = isbf ? ((const ushort_t*)srcs[k])[idx]
                                    : f2bf(((const float*)srcs[k])[idx]);
                return;
            }
            idx -= ns[k];
        }
        return;
    }
    if (isbf) return;                    // x used directly when already bf16
    long long i0 = ((long long)(b - NBZ - 15) * 256 + tid) * 8;
    if (i0 + 8 <= nx) {
        const float* f = (const float*)xin + i0;
        float4 a = *(const float4*)f, bb = *(const float4*)(f + 4);
        ushort_t o[8] = {f2bf(a.x), f2bf(a.y), f2bf(a.z), f2bf(a.w),
                         f2bf(bb.x), f2bf(bb.y), f2bf(bb.z), f2bf(bb.w)};
        *(uint4*)&xc[i0] = *(uint4*)o;
    } else {
        for (long long i = i0; i < nx; ++i) xc[i] = f2bf(((const float*)xin)[i]);
    }
}

// ---------------------------------------------------------------------------
// CSR build by dst
// ---------------------------------------------------------------------------
__global__ void hist_kernel(const int* __restrict__ dst, int* deg, int E, int N) {
    int i = blockIdx.x * blockDim.x + threadIdx.x;
    if (i < E) {
        int d = dst[i];
        if ((uint)d < (uint)N) atomicAdd(&deg[d], 1);
    }
}

// phase 1: per-1024-block exclusive scan over (deg[i] + 1)  [+1 = self-loop]
__global__ __launch_bounds__(256) void scan1(const int* __restrict__ deg, int* __restrict__ part,
                                             int* __restrict__ bsum, int N) {
    __shared__ int tmp[256];
    int b = blockIdx.x, tid = threadIdx.x;
    int i0 = b * 1024 + tid * 4;
    int v[4] = {0, 0, 0, 0};
    if (i0 + 4 <= N) { int4 q = *(const int4*)&deg[i0]; v[0]=q.x+1; v[1]=q.y+1; v[2]=q.z+1; v[3]=q.w+1; }
    else { for (int j = 0; j < 4; ++j) v[j] = (i0 + j < N) ? deg[i0 + j] + 1 : 0; }
    int s0 = v[0], s1 = s0 + v[1], s2 = s1 + v[2], s3 = s2 + v[3];
    tmp[tid] = s3;
    __syncthreads();
    for (int off = 1; off < 256; off <<= 1) {
        int t = (tid >= off) ? tmp[tid - off] : 0;
        __syncthreads();
        tmp[tid] += t;
        __syncthreads();
    }
    int base = tid ? tmp[tid - 1] : 0;
    int e[4] = {base, base + s0, base + s1, base + s2};
    if (i0 + 4 <= N) { *(int4*)&part[i0] = make_int4(e[0], e[1], e[2], e[3]); }
    else { for (int j = 0; j < 4; ++j) if (i0 + j < N) part[i0 + j] = e[j]; }
    if (tid == 255) bsum[b] = tmp[255];
}

// phase 2 (fused): each block wave-scans the Nb block sums itself (Nb <= 64)
__global__ __launch_bounds__(256) void scan3(const int* __restrict__ part, const int* __restrict__ bsum,
                                             int* __restrict__ offsets, int* __restrict__ cursor,
                                             int N, int Nb) {
    __shared__ int s_add, s_tot;
    int b = blockIdx.x, tid = threadIdx.x;
    if (tid < 64) {
        int v = (tid < Nb) ? bsum[tid] : 0;
        int incl = v;
        #pragma unroll
        for (int off = 1; off < 64; off <<= 1) {
            int t = __shfl_up(incl, off);
            if (tid >= off) incl += t;
        }
        if (tid == b) s_add = incl - v;
        if (tid == Nb - 1) s_tot = incl;
    }
    __syncthreads();
    int add = s_add;
    int i0 = b * 1024 + tid * 4;
    #pragma unroll
    for (int j = 0; j < 4; ++j) {
        int i = i0 + j;
        if (i < N) { int o = part[i] + add; offsets[i] = o; cursor[i] = o; }
    }
    if (b == Nb - 1 && tid == 0) offsets[N] = s_tot;   // = E + N
}

__global__ void scatter_kernel(const int* __restrict__ src, const int* __restrict__ dst,
                               int* cursor, int* srcs, int E, int N) {
    int i = blockIdx.x * blockDim.x + threadIdx.x;
    if (i >= E + N) return;
    int s, d;
    if (i < E) { s = src[i]; d = dst[i]; }
    else       { s = i - E; d = i - E; }   // self-loop
    if ((uint)d >= (uint)N) return;
    int pos = atomicAdd(&cursor[d], 1);
    if ((uint)pos < (uint)(E + N)) srcs[pos] = s;
}

// ---------------------------------------------------------------------------
// dual-dtype transpose+canon for BOTH weight matrices in one dispatch (z = 0/1)
// out[N][K] (bf16) = in[K][N] (bf16 or fp32)
// ---------------------------------------------------------------------------
__global__ __launch_bounds__(256) void transpose_canon2(const void* __restrict__ inL,
                                                        const void* __restrict__ inR,
                                                        ushort_t* __restrict__ outL,
                                                        ushort_t* __restrict__ outR,
                                                        const int* __restrict__ flag,
                                                        int K, int N) {
    __shared__ ushort_t t[64][72];
    const void* in = blockIdx.z ? inR : inL;
    ushort_t* outp = blockIdx.z ? outR : outL;
    int k0 = blockIdx.y * 64, n0 = blockIdx.x * 64;
    int tid = threadIdx.x;
    int r = tid >> 3;            // 0..31
    int c = (tid & 7) * 8;       // 0,8,..,56
    int isbf = *flag;
    #pragma unroll
    for (int p = 0; p < 2; ++p) {
        int row = r + p * 32;
        size_t base = (size_t)(k0 + row) * N + n0 + c;
        if (isbf) {
            *(uint4*)&t[row][c] = *(const uint4*)((const ushort_t*)in + base);
        } else {
            const float* f = (const float*)in + base;
            float4 a = *(const float4*)f, b = *(const float4*)(f + 4);
            ushort_t o[8] = {f2bf(a.x), f2bf(a.y), f2bf(a.z), f2bf(a.w),
                             f2bf(b.x), f2bf(b.y), f2bf(b.z), f2bf(b.w)};
            *(uint4*)&t[row][c] = *(uint4*)o;
        }
    }
    __syncthreads();
    #pragma unroll
    for (int p = 0; p < 2; ++p) {
        int row = r + p * 32;
        #pragma unroll
        for (int j = 0; j < 8; ++j)
            outp[(size_t)(n0 + row) * K + k0 + c + j] = t[c + j][row];
    }
}

// ---------------------------------------------------------------------------
// MFMA bf16 GEMM: C[M,N] = A[M,K] @ Bt[N,K]^T. 128x128 tile, 4 waves of 64x64.
// BK=64 via two k-panels per staging iter (r10 structure). Proven 121us on
// this shape. (R2's 256x256 8-phase port measured 134.7us: at K=512 only 8
// K-tiles -> fill/drain dominates, and 128KB LDS -> 1 block/CU kills the
// implicit cross-block TLP that covers ds_read latency here. Reverted.)
// ---------------------------------------------------------------------------
__global__ __launch_bounds__(256) void gemm128(const ushort_t* A_bf, const ushort_t* A_cv,
                                               const int* __restrict__ flag,
                                               const ushort_t* __restrict__ Bt,
                                               ushort_t* __restrict__ C,
                                               int M, int Nn, int K) {
    constexpr int CSTR = 132;                 // epilogue row stride (bank spread)
    __shared__ ushort_t SH[128 * CSTR];       // 33792 B; staging uses first 32KB
    ushort_t* As = SH;                        // As[2][4096]
    ushort_t* Bs = SH + 8192;                 // Bs[2][4096]
    const ushort_t* A = (*flag) ? A_bf : A_cv;
    int tid = threadIdx.x;
    int wave = tid >> 6, lane = tid & 63;
    int row0 = blockIdx.y * 128, col0 = blockIdx.x * 128;
    int wm = (wave >> 1) * 64, wn = (wave & 1) * 64;

    f32x4v acc[4][4];
    #pragma unroll
    for (int i = 0; i < 4; ++i)
        #pragma unroll
        for (int j = 0; j < 4; ++j) acc[i][j] = (f32x4v){0.f, 0.f, 0.f, 0.f};

    int fm = lane & 15, kq8 = (lane >> 4) * 8;

    // staging (r6 mapping, coalesced 64B runs): chunk p -> row=p>>2, kp=p&3
    const ushort_t* srcA[2]; ushort_t* dstA0[2]; ushort_t* dstA1[2];
    const ushort_t* srcB[2]; ushort_t* dstB0[2]; ushort_t* dstB1[2];
    #pragma unroll
    for (int i = 0; i < 2; ++i) {
        int p = (wave * 2 + i) * 64 + lane;
        int row = p >> 2, kp = p & 3;
        int gra = row0 + row; if (gra >= M) gra = M - 1;   // tail clamp (C-write guarded)
        srcA[i] = &A[(size_t)gra * K + kp * 8];
        srcB[i] = &Bt[(size_t)(col0 + row) * K + kp * 8];
        dstA0[i] = &As[p * 8]; dstA1[i] = &As[4096 + p * 8];
        dstB0[i] = &Bs[p * 8]; dstB1[i] = &Bs[4096 + p * 8];
    }

    for (int k0 = 0; k0 < K; k0 += 64) {
        #pragma unroll
        for (int i = 0; i < 2; ++i) {
            __builtin_amdgcn_global_load_lds((g_u32_t*)srcA[i],        (lds_u32_t*)dstA0[i], 16, 0, 0);
            __builtin_amdgcn_global_load_lds((g_u32_t*)(srcA[i] + 32), (lds_u32_t*)dstA1[i], 16, 0, 0);
            __builtin_amdgcn_global_load_lds((g_u32_t*)srcB[i],        (lds_u32_t*)dstB0[i], 16, 0, 0);
            __builtin_amdgcn_global_load_lds((g_u32_t*)(srcB[i] + 32), (lds_u32_t*)dstB1[i], 16, 0, 0);
            srcA[i] += 64; srcB[i] += 64;
        }
        __syncthreads();

        #pragma unroll
        for (int panel = 0; panel < 2; ++panel) {
            bf16x8v af[4], bfr[4];
            #pragma unroll
            for (int mi = 0; mi < 4; ++mi)
                af[mi] = *(const bf16x8v*)&As[panel * 4096 + (wm + mi * 16 + fm) * 32 + kq8];
            #pragma unroll
            for (int nj = 0; nj < 4; ++nj)
                bfr[nj] = *(const bf16x8v*)&Bs[panel * 4096 + (wn + nj * 16 + fm) * 32 + kq8];
            #pragma unroll
            for (int mi = 0; mi < 4; ++mi)
                #pragma unroll
                for (int nj = 0; nj < 4; ++nj)
                    acc[mi][nj] = __builtin_amdgcn_mfma_f32_16x16x32_bf16(af[mi], bfr[nj], acc[mi][nj], 0, 0, 0);
        }
        __syncthreads();
    }

    // epilogue: C/D layout col = lane&15, row = (lane>>4)*4 + r  [verified r4-r14]
    int col = lane & 15, rq = (lane >> 4) * 4;
    #pragma unroll
    for (int mi = 0; mi < 4; ++mi)
        #pragma unroll
        for (int r = 0; r < 4; ++r)
            #pragma unroll
            for (int nj = 0; nj < 4; ++nj)
                SH[(wm + mi * 16 + rq + r) * CSTR + wn + nj * 16 + col] = f2bf(acc[mi][nj][r]);
    __syncthreads();
    #pragma unroll
    for (int j = 0; j < 8; ++j) {
        int base = (tid + j * 256) * 8;        // idx in 128x128 space
        int r = base >> 7, c = base & 127;
        int gm = row0 + r;
        if (gm < M)
            *(uint4*)&C[(size_t)gm * Nn + col0 + c] = *(const uint4*)&SH[r * CSTR + c];
    }
}

// ---------------------------------------------------------------------------
// R4 (= R3 with compile fix): head-split fused edge/softmax/aggregate/
// classifier. TWO dispatches of 2 heads each (hsel = 0, 2). Rationale: gat is
// gather-memory-bound (737MB of random 4KB row fetches from an 82MB xl table
// that SHOULD be L3-resident, yet 386MB hit HBM -> L3 churned by the
// single-use 82MB xr stream + LRU pressure). Splitting heads halves the live
// gather set to 41MB (robustly L3-resident per dispatch); xr rows are loaded
// NONTEMPORAL (read exactly once -> stop evicting xl). Head-mean + classifier
// are linear, so: out = q01 + q23 + bias@Wc + bc; dispatch 1 writes q01 to
// part[], dispatch 2 adds q23 + bias terms and finalizes.
// Block = 64 threads (1 wave) per dst node: lane l -> head hsel+(l>>5),
// channels (l&31)*16..+16 (wave covers a contiguous 2KB of the row).
// Butterfly reduce within 32-lane halves. 2-edge-pair prefetch pipeline.
// Compile fix vs R3: __builtin_nontemporal_load needs ext_vector_type ptr,
// not HIP_vector_type (uint4) -> load via uint4v alias, reinterpret.
// ---------------------------------------------------------------------------
__global__ __launch_bounds__(64, 4) void gat_aggregate2(
    const ushort_t* __restrict__ xl, int xl_stride,
    const ushort_t* __restrict__ xr, int xr_stride,
    const int* __restrict__ offsets, const int* __restrict__ srcs,
    const ushort_t* __restrict__ att, const ushort_t* __restrict__ bias,
    const ushort_t* __restrict__ Wc, const ushort_t* __restrict__ bc,
    float* __restrict__ part, float* __restrict__ out, int hsel,
    int c0, int Cn, int N, int EN) {
    int bn = blockIdx.x;
    if (bn >= Cn) return;
    int n = c0 + bn;
    int lane = threadIdx.x;                  // 0..63
    int hl = lane >> 5, r = lane & 31;
    int hoff = (hsel + hl) * FEAT + r * 16;  // 16 channels per lane

    __shared__ float sh[2][FEAT];

    float2 xrr[8], attr[8];
    { const uint4v* p = (const uint4v*)&xr[(size_t)bn * xr_stride + hoff];
      uint4v qa = __builtin_nontemporal_load(p);          // xr read exactly once
      uint4v qb = __builtin_nontemporal_load(p + 1);
      xrr[0] = up2(qa.x); xrr[1] = up2(qa.y); xrr[2] = up2(qa.z); xrr[3] = up2(qa.w);
      xrr[4] = up2(qb.x); xrr[5] = up2(qb.y); xrr[6] = up2(qb.z); xrr[7] = up2(qb.w); }
    { const ushort_t* p = &att[hoff];
      uint4 qa = *(const uint4*)p, qb = *(const uint4*)(p + 8);
      attr[0] = up2(qa.x); attr[1] = up2(qa.y); attr[2] = up2(qa.z); attr[3] = up2(qa.w);
      attr[4] = up2(qb.x); attr[5] = up2(qb.y); attr[6] = up2(qb.z); attr[7] = up2(qb.w); }

    int start = offsets[n], end = offsets[n + 1];
    start = max(0, min(start, EN));
    end   = max(start, min(end, EN));
    int deg = end - start;

    int sv = 0;
    if (lane < deg) sv = srcs[start + lane];

    float l = 0.f;
    float2 acc[8] = {{0.f,0.f},{0.f,0.f},{0.f,0.f},{0.f,0.f},
                     {0.f,0.f},{0.f,0.f},{0.f,0.f},{0.f,0.f}};
    const ushort_t* xlh = xl + hoff;
    const float2 cneg = make_float2(NEG - 1.0f, NEG - 1.0f);

    auto getS = [&](int i) -> int {
        if (i >= deg) i = deg - 1;
        if (i < 0) i = 0;
        int s = (i < 64) ? __shfl(sv, i) : srcs[start + i];
        return ((uint)s >= (uint)N) ? 0 : s;
    };
    auto fetchE = [&](int i, uint4& qa, uint4& qb) {
        int s = getS(i);
        const ushort_t* pp = xlh + (size_t)s * xl_stride;
        qa = *(const uint4*)pp;
        qb = *(const uint4*)(pp + 8);
    };
    auto body = [&](uint4 qa, uint4 qb) {
        float2 v[8] = {up2(qa.x), up2(qa.y), up2(qa.z), up2(qa.w),
                       up2(qb.x), up2(qb.y), up2(qb.z), up2(qb.w)};
        float2 p2 = make_float2(0.f, 0.f);
        #pragma unroll
        for (int j = 0; j < 8; ++j) {
            float2 u  = f2add(v[j], xrr[j]);
            float2 lr = f2fma(f2min0(u), cneg, u);   // 2-op LeakyReLU (packed)
            p2 = f2fma(lr, attr[j], p2);
        }
        float p = p2.x + p2.y;
        #pragma unroll
        for (int off = 16; off >= 1; off >>= 1) p += __shfl_xor(p, off);  // intra-half
        float wgt = __expf(p);
        l += wgt;
        #pragma unroll
        for (int j = 0; j < 8; ++j) acc[j] = f2fmas(wgt, v[j], acc[j]);
    };

    uint4 a0q, a0r, a1q, a1r, b0q, b0r, b1q, b1r;
    fetchE(0, a0q, a0r);
    fetchE(1, a1q, a1r);
    for (int e = 0; e < deg; e += 2) {
        fetchE(e + 2, b0q, b0r);     // clamped on tail -> L1 hit, discarded
        fetchE(e + 3, b1q, b1r);
        body(a0q, a0r);
        if (e + 1 < deg) body(a1q, a1r);
        a0q = b0q; a0r = b0r; a1q = b1q; a1r = b1r;
    }

    float inv = 0.25f / fmaxf(l, 1e-35f);   // 1/l, mean over heads folded in
    #pragma unroll
    for (int j = 0; j < 8; ++j) {
        sh[hl][r * 16 + 2 * j]     = acc[j].x * inv;
        sh[hl][r * 16 + 2 * j + 1] = acc[j].y * inv;
    }
    __syncthreads();

    // classifier partial over this dispatch's 2 heads
    float p0 = 0.f, p1 = 0.f;
    #pragma unroll
    for (int c = lane; c < FEAT; c += 64) {
        float f = sh[0][c] + sh[1][c];
        if (hsel) f += bf2f(bias[c]);        // bias terms added exactly once
        uint w2 = *(const uint*)&Wc[c * 2];
        p0 = fmaf(f, bf2f((ushort_t)(w2 & 0xffff)), p0);
        p1 = fmaf(f, bf2f((ushort_t)(w2 >> 16)), p1);
    }
    #pragma unroll
    for (int off = 32; off >= 1; off >>= 1) {
        p0 += __shfl_xor(p0, off);
        p1 += __shfl_xor(p1, off);
    }
    if (lane == 0) {
        if (!hsel) {
            __builtin_nontemporal_store(p0, &part[(size_t)n * 2 + 0]);
            __builtin_nontemporal_store(p1, &part[(size_t)n * 2 + 1]);
        } else {
            out[(size_t)n * 2 + 0] = part[(size_t)n * 2 + 0] + p0 + bf2f(bc[0]);
            out[(size_t)n * 2 + 1] = part[(size_t)n * 2 + 1] + p1 + bf2f(bc[1]);
        }
    }
}

// ---------------------------------------------------------------------------
extern "C" void kernel_launch(void* const* d_in, const int* in_sizes, int n_in,
                              void* d_out, int out_size, void* d_ws, size_t ws_size,
                              hipStream_t stream) {
    const void* x    = d_in[0];
    const int*  ei   = (const int*)d_in[1];
    const void* W_l  = d_in[2];
    const void* W_r  = d_in[3];
    const void* att  = d_in[4];
    const void* bias = d_in[5];
    const void* Wc   = d_in[6];
    const void* bc   = d_in[7];
    float* out = (float*)d_out;

    const int N  = in_sizes[0] / FEAT;     // 20000
    const int E  = in_sizes[1] / 2;        // 160000
    const int K  = FEAT;                   // 512
    const int HC = HEADS * FEAT;           // 2048
    const int EN = E + N;
    const int Nb = (N + 1023) / 1024;      // scan blocks (20 <= 64)

    const int* src = ei;
    const int* dst = ei + E;

    // ---- adaptive workspace layout ----
    char* base = (char*)d_ws;
    size_t off = 0;
    auto alloc = [&](size_t bytes) -> char* {
        char* p = base + off;
        off = (off + bytes + 255) & ~(size_t)255;
        return p;
    };
    int* flag    = (int*)alloc(4);
    int* offsets = (int*)alloc((size_t)(N + 1) * 4);
    int* cursor  = (int*)alloc((size_t)N * 4);
    int* deg     = (int*)alloc((size_t)N * 4);
    int* part    = (int*)alloc((size_t)N * 4);
    int* bsum    = (int*)alloc((size_t)(Nb + 1) * 4);
    int* srcs    = (int*)alloc((size_t)EN * 4);
    float* hpart = (float*)alloc((size_t)N * 2 * 4);             // head-split partial
    ushort_t* attc  = (ushort_t*)alloc((size_t)HC * 2);
    ushort_t* biasc = (ushort_t*)alloc((size_t)FEAT * 2);
    ushort_t* Wcc   = (ushort_t*)alloc((size_t)FEAT * 2 * 2);
    ushort_t* bcc   = (ushort_t*)alloc(2 * 2);
    ushort_t* xc   = (ushort_t*)alloc((size_t)N * K * 2);
    ushort_t* Wcat = (ushort_t*)alloc((size_t)2 * HC * K * 2);   // [Wl^T ; Wr^T]
    size_t fixed = off;

    size_t need_merged = (size_t)N * 2 * HC * 2;
    bool merged = (ws_size >= fixed + need_merged);

    // 0) fused prep: probe + deg-zero + small canon + x canon (1 dispatch)
    long long NX = (long long)N * K;
    const int NBZ = (N + 1023) / 1024;                       // deg-zero blocks
    int nxb = (int)((NX / 8 + 255) / 256);                   // x canon blocks
    prep_kernel<<<NBZ + 15 + nxb, 256, 0, stream>>>(
        (const ushort_t*)x, flag, deg, N, NBZ,
        att, attc, HC, bias, biasc, FEAT, Wc, Wcc, FEAT * 2, bc, bcc, 2,
        x, xc, NX);

    // 1) CSR build
    hist_kernel<<<(E + 255) / 256, 256, 0, stream>>>(dst, deg, E, N);
    scan1<<<Nb, 256, 0, stream>>>(deg, part, bsum, N);
    scan3<<<Nb, 256, 0, stream>>>(part, bsum, offsets, cursor, N, Nb);
    scatter_kernel<<<(EN + 255) / 256, 256, 0, stream>>>(src, dst, cursor, srcs, E, N);

    // 2) transpose+canon both weights in one dispatch
    dim3 tg(HC / 64, K / 64, 2);
    transpose_canon2<<<tg, 256, 0, stream>>>(W_l, W_r, Wcat, Wcat + (size_t)HC * K,
                                             flag, K, HC);

    const ushort_t* x_bf = (const ushort_t*)x;

    if (merged) {
        ushort_t* xlr = (ushort_t*)(base + fixed);       // N x 4096: [xl | xr]
        dim3 gg(2 * HC / 128, (N + 127) / 128);          // x = col tiles (r10 order)
        gemm128<<<gg, 256, 0, stream>>>(x_bf, xc, flag, Wcat, xlr, N, 2 * HC, K);
        gat_aggregate2<<<N, 64, 0, stream>>>(xlr, 2 * HC, xlr + HC, 2 * HC,
                                             offsets, srcs, attc, biasc, Wcc, bcc,
                                             hpart, out, 0, 0, N, N, EN);
        gat_aggregate2<<<N, 64, 0, stream>>>(xlr, 2 * HC, xlr + HC, 2 * HC,
                                             offsets, srcs, attc, biasc, Wcc, bcc,
                                             hpart, out, 2, 0, N, N, EN);
    } else {
        // fallback: separate xl + chunked xr
        ushort_t* xl = (ushort_t*)alloc((size_t)N * HC * 2);
        size_t remain = (ws_size > off) ? (ws_size - off) : 0;
        long long Cmax = (long long)(remain / ((size_t)HC * 2));
        int C = (Cmax >= N) ? N : (int)(Cmax & ~63LL);
        if (C < 64) C = 64;
        ushort_t* xrc = (ushort_t*)(base + off);
        ushort_t* Wlt = Wcat;
        ushort_t* Wrt = Wcat + (size_t)HC * K;

        dim3 gl(HC / 128, (N + 127) / 128);
        gemm128<<<gl, 256, 0, stream>>>(x_bf, xc, flag, Wlt, xl, N, HC, K);
        for (int c0 = 0; c0 < N; c0 += C) {
            int Cn = (N - c0 < C) ? (N - c0) : C;
            dim3 gr(HC / 128, (Cn + 127) / 128);
            gemm128<<<gr, 256, 0, stream>>>(x_bf + (size_t)c0 * K, xc + (size_t)c0 * K, flag,
                                            Wrt, xrc, Cn, HC, K);
            gat_aggregate2<<<Cn, 64, 0, stream>>>(xl, HC, xrc, HC,
                                                  offsets, srcs, attc, biasc, Wcc, bcc,
                                                  hpart, out, 0, c0, Cn, N, EN);
            gat_aggregate2<<<Cn, 64, 0, stream>>>(xl, HC, xrc, HC,
                                                  offsets, srcs, attc, biasc, Wcc, bcc,
                                                  hpart, out, 2, c0, Cn, N, EN);
        }
    }
}

// Round 5
// 331.290 us; speedup vs baseline: 1.0506x; 1.0506x over previous
//
#include <hip/hip_runtime.h>
#include <hip/hip_bf16.h>

#define FEAT    512
#define HEADS   4
#define NEG     0.2f

typedef unsigned int uint;
typedef unsigned short ushort_t;
typedef __attribute__((ext_vector_type(8))) short bf16x8v;   // 8 bf16 = 4 VGPRs
typedef __attribute__((ext_vector_type(4))) float f32x4v;    // mfma acc
typedef __attribute__((ext_vector_type(4))) uint uint4v;     // nt-load-able 16B
typedef __attribute__((address_space(3))) uint lds_u32_t;
typedef __attribute__((address_space(1))) const uint g_u32_t;

__device__ inline float bf2f(ushort_t h) { return __uint_as_float(((uint)h) << 16); }
__device__ inline ushort_t f2bf(float f) {
    uint u = __float_as_uint(f);
    u += 0x7fff + ((u >> 16) & 1);           // RNE
    return (ushort_t)(u >> 16);
}
__device__ inline float2 up2(uint d) {       // 2 packed bf16 -> float2, 2 inst
    return make_float2(__uint_as_float(d << 16), __uint_as_float(d & 0xffff0000u));
}
__device__ inline float2 f2add(float2 a, float2 b) { return make_float2(a.x + b.x, a.y + b.y); }
__device__ inline float2 f2min0(float2 a) { return make_float2(fminf(a.x, 0.f), fminf(a.y, 0.f)); }
__device__ inline float2 f2fma(float2 a, float2 b, float2 c) {
    return make_float2(fmaf(a.x, b.x, c.x), fmaf(a.y, b.y, c.y));
}
__device__ inline float2 f2fmas(float s, float2 b, float2 c) {
    return make_float2(fmaf(s, b.x, c.x), fmaf(s, b.y, c.y));
}

// ---------------------------------------------------------------------------
// fused prep (R5): dtype probe + deg zeroing + small-array canon + BOTH weight
// transposes + x canon, all in 1 dispatch. Each block probes dtype itself from
// the same 256B of x, so the W-transpose role has no cross-dispatch flag dep.
// block roles: [0,NBZ) zero deg | [NBZ,NBZ+15) canon small4 |
//              [NBZ+15, NBZ+15+nT) W transpose | rest: x canon.
// ---------------------------------------------------------------------------
__global__ __launch_bounds__(256) void prep_kernel(
    const ushort_t* __restrict__ xprobe, int* flag,
    int* __restrict__ deg, int N, int NBZ,
    const void* a0, ushort_t* o0, int n0, const void* a1, ushort_t* o1, int n1,
    const void* a2, ushort_t* o2, int n2, const void* a3, ushort_t* o3, int n3,
    const void* __restrict__ Wl, const void* __restrict__ Wr,
    ushort_t* __restrict__ WtL, ushort_t* __restrict__ WtR, int Kk, int HCk, int nT,
    const void* __restrict__ xin, ushort_t* __restrict__ xc, long long nx) {
    __shared__ int s_isbf;
    __shared__ ushort_t t[64][72];
    int tid = threadIdx.x;
    if (tid < 64) {
        int hits = 0;
        for (int i = tid; i < 128; i += 64) {
            ushort_t w = xprobe[2 * i];
            uint hb = (w >> 8) & 0x7f;
            hits += (hb >= 0x38 && hb <= 0x42) ? 1 : 0;
        }
        #pragma unroll
        for (int off = 32; off >= 1; off >>= 1) hits += __shfl_xor(hits, off);
        if (tid == 0) s_isbf = (hits >= 64) ? 1 : 0;
    }
    __syncthreads();
    int isbf = s_isbf;
    int b = blockIdx.x;
    if (b == 0 && tid == 0) *flag = isbf;

    if (b < NBZ) {                       // zero deg (int4)
        int i0 = (b * 256 + tid) * 4;
        if (i0 + 4 <= N) *(int4*)&deg[i0] = make_int4(0, 0, 0, 0);
        else for (int j = 0; j < 4; ++j) if (i0 + j < N) deg[i0 + j] = 0;
        return;
    }
    if (b < NBZ + 15) {                  // canon small4
        int idx = (b - NBZ) * 256 + tid;
        const void* srcs[4] = {a0, a1, a2, a3};
        ushort_t* dsts[4] = {o0, o1, o2, o3};
        int ns[4] = {n0, n1, n2, n3};
        #pragma unroll
        for (int k = 0; k < 4; ++k) {
            if (idx < ns[k]) {
                dsts[k][idx] = isbf ? ((const ushort_t*)srcs[k])[idx]
                                    : f2bf(((const float*)srcs[k])[idx]);
                return;
            }
            idx -= ns[k];
        }
        return;
    }
    if (b < NBZ + 15 + nT) {             // W transpose+canon: out[HC][K] = in[K][HC]
        int b2 = b - (NBZ + 15);
        int z = b2 & 1;
        int rest = b2 >> 1;
        int ntk = Kk >> 6;               // K/64 tiles
        int ky = rest % ntk, nxt = rest / ntk;
        const void* in = z ? Wr : Wl;
        ushort_t* outp = z ? WtR : WtL;
        int k0 = ky * 64, n0 = nxt * 64;
        int r = tid >> 3;                // 0..31
        int c = (tid & 7) * 8;           // 0,8,..,56
        #pragma unroll
        for (int p = 0; p < 2; ++p) {
            int row = r + p * 32;
            size_t base = (size_t)(k0 + row) * HCk + n0 + c;
            if (isbf) {
                *(uint4*)&t[row][c] = *(const uint4*)((const ushort_t*)in + base);
            } else {
                const float* f = (const float*)in + base;
                float4 a = *(const float4*)f, bb = *(const float4*)(f + 4);
                ushort_t o[8] = {f2bf(a.x), f2bf(a.y), f2bf(a.z), f2bf(a.w),
                                 f2bf(bb.x), f2bf(bb.y), f2bf(bb.z), f2bf(bb.w)};
                *(uint4*)&t[row][c] = *(uint4*)o;
            }
        }
        __syncthreads();
        #pragma unroll
        for (int p = 0; p < 2; ++p) {
            int row = r + p * 32;
            #pragma unroll
            for (int j = 0; j < 8; ++j)
                outp[(size_t)(n0 + row) * Kk + k0 + c + j] = t[c + j][row];
        }
        return;
    }
    if (isbf) return;                    // x used directly when already bf16
    long long i0 = ((long long)(b - NBZ - 15 - nT) * 256 + tid) * 8;
    if (i0 + 8 <= nx) {
        const float* f = (const float*)xin + i0;
        float4 a = *(const float4*)f, bb = *(const float4*)(f + 4);
        ushort_t o[8] = {f2bf(a.x), f2bf(a.y), f2bf(a.z), f2bf(a.w),
                         f2bf(bb.x), f2bf(bb.y), f2bf(bb.z), f2bf(bb.w)};
        *(uint4*)&xc[i0] = *(uint4*)o;
    } else {
        for (long long i = i0; i < nx; ++i) xc[i] = f2bf(((const float*)xin)[i]);
    }
}

// ---------------------------------------------------------------------------
// CSR build by dst
// ---------------------------------------------------------------------------
__global__ void hist_kernel(const int* __restrict__ dst, int* deg, int E, int N) {
    int i = blockIdx.x * blockDim.x + threadIdx.x;
    if (i < E) {
        int d = dst[i];
        if ((uint)d < (uint)N) atomicAdd(&deg[d], 1);
    }
}

// phase 1: per-1024-block exclusive scan over (deg[i] + 1)  [+1 = self-loop]
__global__ __launch_bounds__(256) void scan1(const int* __restrict__ deg, int* __restrict__ part,
                                             int* __restrict__ bsum, int N) {
    __shared__ int tmp[256];
    int b = blockIdx.x, tid = threadIdx.x;
    int i0 = b * 1024 + tid * 4;
    int v[4] = {0, 0, 0, 0};
    if (i0 + 4 <= N) { int4 q = *(const int4*)&deg[i0]; v[0]=q.x+1; v[1]=q.y+1; v[2]=q.z+1; v[3]=q.w+1; }
    else { for (int j = 0; j < 4; ++j) v[j] = (i0 + j < N) ? deg[i0 + j] + 1 : 0; }
    int s0 = v[0], s1 = s0 + v[1], s2 = s1 + v[2], s3 = s2 + v[3];
    tmp[tid] = s3;
    __syncthreads();
    for (int off = 1; off < 256; off <<= 1) {
        int t = (tid >= off) ? tmp[tid - off] : 0;
        __syncthreads();
        tmp[tid] += t;
        __syncthreads();
    }
    int base = tid ? tmp[tid - 1] : 0;
    int e[4] = {base, base + s0, base + s1, base + s2};
    if (i0 + 4 <= N) { *(int4*)&part[i0] = make_int4(e[0], e[1], e[2], e[3]); }
    else { for (int j = 0; j < 4; ++j) if (i0 + j < N) part[i0 + j] = e[j]; }
    if (tid == 255) bsum[b] = tmp[255];
}

// phase 2 (fused): each block wave-scans the Nb block sums itself (Nb <= 64)
__global__ __launch_bounds__(256) void scan3(const int* __restrict__ part, const int* __restrict__ bsum,
                                             int* __restrict__ offsets, int* __restrict__ cursor,
                                             int N, int Nb) {
    __shared__ int s_add, s_tot;
    int b = blockIdx.x, tid = threadIdx.x;
    if (tid < 64) {
        int v = (tid < Nb) ? bsum[tid] : 0;
        int incl = v;
        #pragma unroll
        for (int off = 1; off < 64; off <<= 1) {
            int t = __shfl_up(incl, off);
            if (tid >= off) incl += t;
        }
        if (tid == b) s_add = incl - v;
        if (tid == Nb - 1) s_tot = incl;
    }
    __syncthreads();
    int add = s_add;
    int i0 = b * 1024 + tid * 4;
    #pragma unroll
    for (int j = 0; j < 4; ++j) {
        int i = i0 + j;
        if (i < N) { int o = part[i] + add; offsets[i] = o; cursor[i] = o; }
    }
    if (b == Nb - 1 && tid == 0) offsets[N] = s_tot;   // = E + N
}

__global__ void scatter_kernel(const int* __restrict__ src, const int* __restrict__ dst,
                               int* cursor, int* srcs, int E, int N) {
    int i = blockIdx.x * blockDim.x + threadIdx.x;
    if (i >= E + N) return;
    int s, d;
    if (i < E) { s = src[i]; d = dst[i]; }
    else       { s = i - E; d = i - E; }   // self-loop
    if ((uint)d >= (uint)N) return;
    int pos = atomicAdd(&cursor[d], 1);
    if ((uint)pos < (uint)(E + N)) srcs[pos] = s;
}

// ---------------------------------------------------------------------------
// MFMA bf16 GEMM: C[M,N] = A[M,K] @ Bt[N,K]^T. 128x128 tile, 4 waves of 64x64.
// BK=64 via two k-panels per staging iter (r10 structure). Proven 117us on
// this shape. (R2's 256x256 8-phase port measured 134.7us: at K=512 only 8
// K-tiles -> fill/drain dominates, and 128KB LDS -> 1 block/CU kills the
// implicit cross-block TLP that covers ds_read latency here. Reverted.)
// ---------------------------------------------------------------------------
__global__ __launch_bounds__(256) void gemm128(const ushort_t* A_bf, const ushort_t* A_cv,
                                               const int* __restrict__ flag,
                                               const ushort_t* __restrict__ Bt,
                                               ushort_t* __restrict__ C,
                                               int M, int Nn, int K) {
    constexpr int CSTR = 132;                 // epilogue row stride (bank spread)
    __shared__ ushort_t SH[128 * CSTR];       // 33792 B; staging uses first 32KB
    ushort_t* As = SH;                        // As[2][4096]
    ushort_t* Bs = SH + 8192;                 // Bs[2][4096]
    const ushort_t* A = (*flag) ? A_bf : A_cv;
    int tid = threadIdx.x;
    int wave = tid >> 6, lane = tid & 63;
    int row0 = blockIdx.y * 128, col0 = blockIdx.x * 128;
    int wm = (wave >> 1) * 64, wn = (wave & 1) * 64;

    f32x4v acc[4][4];
    #pragma unroll
    for (int i = 0; i < 4; ++i)
        #pragma unroll
        for (int j = 0; j < 4; ++j) acc[i][j] = (f32x4v){0.f, 0.f, 0.f, 0.f};

    int fm = lane & 15, kq8 = (lane >> 4) * 8;

    // staging (r6 mapping, coalesced 64B runs): chunk p -> row=p>>2, kp=p&3
    const ushort_t* srcA[2]; ushort_t* dstA0[2]; ushort_t* dstA1[2];
    const ushort_t* srcB[2]; ushort_t* dstB0[2]; ushort_t* dstB1[2];
    #pragma unroll
    for (int i = 0; i < 2; ++i) {
        int p = (wave * 2 + i) * 64 + lane;
        int row = p >> 2, kp = p & 3;
        int gra = row0 + row; if (gra >= M) gra = M - 1;   // tail clamp (C-write guarded)
        srcA[i] = &A[(size_t)gra * K + kp * 8];
        srcB[i] = &Bt[(size_t)(col0 + row) * K + kp * 8];
        dstA0[i] = &As[p * 8]; dstA1[i] = &As[4096 + p * 8];
        dstB0[i] = &Bs[p * 8]; dstB1[i] = &Bs[4096 + p * 8];
    }

    for (int k0 = 0; k0 < K; k0 += 64) {
        #pragma unroll
        for (int i = 0; i < 2; ++i) {
            __builtin_amdgcn_global_load_lds((g_u32_t*)srcA[i],        (lds_u32_t*)dstA0[i], 16, 0, 0);
            __builtin_amdgcn_global_load_lds((g_u32_t*)(srcA[i] + 32), (lds_u32_t*)dstA1[i], 16, 0, 0);
            __builtin_amdgcn_global_load_lds((g_u32_t*)srcB[i],        (lds_u32_t*)dstB0[i], 16, 0, 0);
            __builtin_amdgcn_global_load_lds((g_u32_t*)(srcB[i] + 32), (lds_u32_t*)dstB1[i], 16, 0, 0);
            srcA[i] += 64; srcB[i] += 64;
        }
        __syncthreads();

        #pragma unroll
        for (int panel = 0; panel < 2; ++panel) {
            bf16x8v af[4], bfr[4];
            #pragma unroll
            for (int mi = 0; mi < 4; ++mi)
                af[mi] = *(const bf16x8v*)&As[panel * 4096 + (wm + mi * 16 + fm) * 32 + kq8];
            #pragma unroll
            for (int nj = 0; nj < 4; ++nj)
                bfr[nj] = *(const bf16x8v*)&Bs[panel * 4096 + (wn + nj * 16 + fm) * 32 + kq8];
            #pragma unroll
            for (int mi = 0; mi < 4; ++mi)
                #pragma unroll
                for (int nj = 0; nj < 4; ++nj)
                    acc[mi][nj] = __builtin_amdgcn_mfma_f32_16x16x32_bf16(af[mi], bfr[nj], acc[mi][nj], 0, 0, 0);
        }
        __syncthreads();
    }

    // epilogue: C/D layout col = lane&15, row = (lane>>4)*4 + r  [verified r4-r14]
    int col = lane & 15, rq = (lane >> 4) * 4;
    #pragma unroll
    for (int mi = 0; mi < 4; ++mi)
        #pragma unroll
        for (int r = 0; r < 4; ++r)
            #pragma unroll
            for (int nj = 0; nj < 4; ++nj)
                SH[(wm + mi * 16 + rq + r) * CSTR + wn + nj * 16 + col] = f2bf(acc[mi][nj][r]);
    __syncthreads();
    #pragma unroll
    for (int j = 0; j < 8; ++j) {
        int base = (tid + j * 256) * 8;        // idx in 128x128 space
        int r = base >> 7, c = base & 127;
        int gm = row0 + r;
        if (gm < M)
            *(uint4*)&C[(size_t)gm * Nn + col0 + c] = *(const uint4*)&SH[r * CSTR + c];
    }
}

// ---------------------------------------------------------------------------
// R5 gat: single dispatch again (R4's head-split cost +24us: per-edge fixed
// work duplicated, L3 already held the whole table -> no locality win).
// R1 layout: block = 128 threads = 2 waves per dst node; wave w owns heads
// 2w,2w+1; lane l: head 2w+(l>>5), channels (l&31)*16..+16 (contiguous 2KB
// per wave -> coalesced). 5-step butterfly within 32-lane halves. 2-edge-pair
// prefetch pipeline. xr loaded NONTEMPORAL (single-use stream; don't evict
// the xl gather table from L2/L3). OUTPUT FP32.
// ---------------------------------------------------------------------------
__global__ __launch_bounds__(128, 4) void gat_aggregate(
    const ushort_t* __restrict__ xl, int xl_stride,
    const ushort_t* __restrict__ xr, int xr_stride,
    const int* __restrict__ offsets, const int* __restrict__ srcs,
    const ushort_t* __restrict__ att, const ushort_t* __restrict__ bias,
    const ushort_t* __restrict__ Wc, const ushort_t* __restrict__ bc,
    float* __restrict__ out, int c0, int Cn, int N, int EN) {
    int bn = blockIdx.x;
    if (bn >= Cn) return;
    int n = c0 + bn;
    int tid = threadIdx.x;
    int w = tid >> 6, lane = tid & 63;
    int h = 2 * w + (lane >> 5);             // this lane's head
    int r = lane & 31;                       // 32 lanes per head
    int hoff = h * FEAT + r * 16;            // 16 channels per lane

    __shared__ float sh[HEADS][FEAT];
    __shared__ float r0s[2], r1s[2];

    float2 xrr[8], attr[8];
    { const uint4v* p = (const uint4v*)&xr[(size_t)bn * xr_stride + hoff];
      uint4v qa = __builtin_nontemporal_load(p);          // xr read exactly once
      uint4v qb = __builtin_nontemporal_load(p + 1);
      xrr[0] = up2(qa.x); xrr[1] = up2(qa.y); xrr[2] = up2(qa.z); xrr[3] = up2(qa.w);
      xrr[4] = up2(qb.x); xrr[5] = up2(qb.y); xrr[6] = up2(qb.z); xrr[7] = up2(qb.w); }
    { const ushort_t* p = &att[hoff];
      uint4 qa = *(const uint4*)p, qb = *(const uint4*)(p + 8);
      attr[0] = up2(qa.x); attr[1] = up2(qa.y); attr[2] = up2(qa.z); attr[3] = up2(qa.w);
      attr[4] = up2(qb.x); attr[5] = up2(qb.y); attr[6] = up2(qb.z); attr[7] = up2(qb.w); }

    int start = offsets[n], end = offsets[n + 1];
    start = max(0, min(start, EN));
    end   = max(start, min(end, EN));
    int deg = end - start;

    int sv = 0;
    if (lane < deg) sv = srcs[start + lane];

    float l = 0.f;
    float2 acc[8] = {{0.f,0.f},{0.f,0.f},{0.f,0.f},{0.f,0.f},
                     {0.f,0.f},{0.f,0.f},{0.f,0.f},{0.f,0.f}};
    const ushort_t* xlh = xl + hoff;
    const float2 cneg = make_float2(NEG - 1.0f, NEG - 1.0f);

    auto getS = [&](int i) -> int {
        if (i >= deg) i = deg - 1;
        if (i < 0) i = 0;
        int s = (i < 64) ? __shfl(sv, i) : srcs[start + i];
        return ((uint)s >= (uint)N) ? 0 : s;
    };
    auto fetchE = [&](int i, uint4& qa, uint4& qb) {
        int s = getS(i);
        const ushort_t* pp = xlh + (size_t)s * xl_stride;
        qa = *(const uint4*)pp;
        qb = *(const uint4*)(pp + 8);
    };
    auto body = [&](uint4 qa, uint4 qb) {
        float2 v[8] = {up2(qa.x), up2(qa.y), up2(qa.z), up2(qa.w),
                       up2(qb.x), up2(qb.y), up2(qb.z), up2(qb.w)};
        float2 p2 = make_float2(0.f, 0.f);
        #pragma unroll
        for (int j = 0; j < 8; ++j) {
            float2 u  = f2add(v[j], xrr[j]);
            float2 lr = f2fma(f2min0(u), cneg, u);   // 2-op LeakyReLU (packed)
            p2 = f2fma(lr, attr[j], p2);
        }
        float p = p2.x + p2.y;
        #pragma unroll
        for (int off = 16; off >= 1; off >>= 1) p += __shfl_xor(p, off);  // intra-half
        float wgt = __expf(p);
        l += wgt;
        #pragma unroll
        for (int j = 0; j < 8; ++j) acc[j] = f2fmas(wgt, v[j], acc[j]);
    };

    uint4 a0q, a0r, a1q, a1r, b0q, b0r, b1q, b1r;
    fetchE(0, a0q, a0r);
    fetchE(1, a1q, a1r);
    for (int e = 0; e < deg; e += 2) {
        fetchE(e + 2, b0q, b0r);     // clamped on tail -> L1 hit, discarded
        fetchE(e + 3, b1q, b1r);
        body(a0q, a0r);
        if (e + 1 < deg) body(a1q, a1r);
        a0q = b0q; a0r = b0r; a1q = b1q; a1r = b1r;
    }

    float inv = 0.25f / fmaxf(l, 1e-35f);   // 1/l, mean over heads folded in
    #pragma unroll
    for (int j = 0; j < 8; ++j) {
        sh[h][r * 16 + 2 * j]     = acc[j].x * inv;
        sh[h][r * 16 + 2 * j + 1] = acc[j].y * inv;
    }
    __syncthreads();

    float p0 = 0.f, p1 = 0.f;
    #pragma unroll
    for (int c = tid; c < FEAT; c += 128) {
        float f = sh[0][c] + sh[1][c] + sh[2][c] + sh[3][c] + bf2f(bias[c]);
        uint w2 = *(const uint*)&Wc[c * 2];
        p0 = fmaf(f, bf2f((ushort_t)(w2 & 0xffff)), p0);
        p1 = fmaf(f, bf2f((ushort_t)(w2 >> 16)), p1);
    }
    #pragma unroll
    for (int off = 32; off >= 1; off >>= 1) {
        p0 += __shfl_xor(p0, off);
        p1 += __shfl_xor(p1, off);
    }
    if (lane == 0) { r0s[w] = p0; r1s[w] = p1; }
    __syncthreads();
    if (tid == 0) {
        out[(size_t)n * 2 + 0] = r0s[0] + r0s[1] + bf2f(bc[0]);
        out[(size_t)n * 2 + 1] = r1s[0] + r1s[1] + bf2f(bc[1]);
    }
}

// ---------------------------------------------------------------------------
extern "C" void kernel_launch(void* const* d_in, const int* in_sizes, int n_in,
                              void* d_out, int out_size, void* d_ws, size_t ws_size,
                              hipStream_t stream) {
    const void* x    = d_in[0];
    const int*  ei   = (const int*)d_in[1];
    const void* W_l  = d_in[2];
    const void* W_r  = d_in[3];
    const void* att  = d_in[4];
    const void* bias = d_in[5];
    const void* Wc   = d_in[6];
    const void* bc   = d_in[7];
    float* out = (float*)d_out;

    const int N  = in_sizes[0] / FEAT;     // 20000
    const int E  = in_sizes[1] / 2;        // 160000
    const int K  = FEAT;                   // 512
    const int HC = HEADS * FEAT;           // 2048
    const int EN = E + N;
    const int Nb = (N + 1023) / 1024;      // scan blocks (20 <= 64)

    const int* src = ei;
    const int* dst = ei + E;

    // ---- adaptive workspace layout ----
    char* base = (char*)d_ws;
    size_t off = 0;
    auto alloc = [&](size_t bytes) -> char* {
        char* p = base + off;
        off = (off + bytes + 255) & ~(size_t)255;
        return p;
    };
    int* flag    = (int*)alloc(4);
    int* offsets = (int*)alloc((size_t)(N + 1) * 4);
    int* cursor  = (int*)alloc((size_t)N * 4);
    int* deg     = (int*)alloc((size_t)N * 4);
    int* part    = (int*)alloc((size_t)N * 4);
    int* bsum    = (int*)alloc((size_t)(Nb + 1) * 4);
    int* srcs    = (int*)alloc((size_t)EN * 4);
    ushort_t* attc  = (ushort_t*)alloc((size_t)HC * 2);
    ushort_t* biasc = (ushort_t*)alloc((size_t)FEAT * 2);
    ushort_t* Wcc   = (ushort_t*)alloc((size_t)FEAT * 2 * 2);
    ushort_t* bcc   = (ushort_t*)alloc(2 * 2);
    ushort_t* xc   = (ushort_t*)alloc((size_t)N * K * 2);
    ushort_t* Wcat = (ushort_t*)alloc((size_t)2 * HC * K * 2);   // [Wl^T ; Wr^T]
    size_t fixed = off;

    size_t need_merged = (size_t)N * 2 * HC * 2;
    bool merged = (ws_size >= fixed + need_merged);

    // 0) fused prep: probe + deg-zero + small canon + W transpose + x canon
    long long NX = (long long)N * K;
    const int NBZ = (N + 1023) / 1024;                       // deg-zero blocks
    const int nT = (HC / 64) * (K / 64) * 2;                 // 512 transpose blocks
    int nxb = (int)((NX / 8 + 255) / 256);                   // x canon blocks
    prep_kernel<<<NBZ + 15 + nT + nxb, 256, 0, stream>>>(
        (const ushort_t*)x, flag, deg, N, NBZ,
        att, attc, HC, bias, biasc, FEAT, Wc, Wcc, FEAT * 2, bc, bcc, 2,
        W_l, W_r, Wcat, Wcat + (size_t)HC * K, K, HC, nT,
        x, xc, NX);

    // 1) CSR build
    hist_kernel<<<(E + 255) / 256, 256, 0, stream>>>(dst, deg, E, N);
    scan1<<<Nb, 256, 0, stream>>>(deg, part, bsum, N);
    scan3<<<Nb, 256, 0, stream>>>(part, bsum, offsets, cursor, N, Nb);
    scatter_kernel<<<(EN + 255) / 256, 256, 0, stream>>>(src, dst, cursor, srcs, E, N);

    const ushort_t* x_bf = (const ushort_t*)x;

    if (merged) {
        ushort_t* xlr = (ushort_t*)(base + fixed);       // N x 4096: [xl | xr]
        dim3 gg(2 * HC / 128, (N + 127) / 128);          // x = col tiles (r10 order)
        gemm128<<<gg, 256, 0, stream>>>(x_bf, xc, flag, Wcat, xlr, N, 2 * HC, K);
        gat_aggregate<<<N, 128, 0, stream>>>(xlr, 2 * HC, xlr + HC, 2 * HC,
                                             offsets, srcs, attc, biasc, Wcc, bcc,
                                             out, 0, N, N, EN);
    } else {
        // fallback: separate xl + chunked xr
        ushort_t* xl = (ushort_t*)alloc((size_t)N * HC * 2);
        size_t remain = (ws_size > off) ? (ws_size - off) : 0;
        long long Cmax = (long long)(remain / ((size_t)HC * 2));
        int C = (Cmax >= N) ? N : (int)(Cmax & ~63LL);
        if (C < 64) C = 64;
        ushort_t* xrc = (ushort_t*)(base + off);
        ushort_t* Wlt = Wcat;
        ushort_t* Wrt = Wcat + (size_t)HC * K;

        dim3 gl(HC / 128, (N + 127) / 128);
        gemm128<<<gl, 256, 0, stream>>>(x_bf, xc, flag, Wlt, xl, N, HC, K);
        for (int c0 = 0; c0 < N; c0 += C) {
            int Cn = (N - c0 < C) ? (N - c0) : C;
            dim3 gr(HC / 128, (Cn + 127) / 128);
            gemm128<<<gr, 256, 0, stream>>>(x_bf + (size_t)c0 * K, xc + (size_t)c0 * K, flag,
                                            Wrt, xrc, Cn, HC, K);
            gat_aggregate<<<Cn, 128, 0, stream>>>(xl, HC, xrc, HC,
                                                  offsets, srcs, attc, biasc, Wcc, bcc,
                                                  out, c0, Cn, N, EN);
        }
    }
}

// Round 7
// 320.932 us; speedup vs baseline: 1.0845x; 1.0323x over previous
//
#include <hip/hip_runtime.h>
#include <hip/hip_bf16.h>

#define FEAT    512
#define HEADS   4
#define NEG     0.2f

typedef unsigned int uint;
typedef unsigned short ushort_t;
typedef __attribute__((ext_vector_type(8))) short bf16x8v;   // 8 bf16 = 4 VGPRs
typedef __attribute__((ext_vector_type(4))) float f32x4v;    // mfma acc
typedef __attribute__((ext_vector_type(2))) float f32x2v;    // packed-f32 pair
typedef __attribute__((ext_vector_type(4))) uint uint4v;     // nt-load-able 16B
typedef __attribute__((address_space(3))) uint lds_u32_t;
typedef __attribute__((address_space(1))) const uint g_u32_t;

__device__ inline float bf2f(ushort_t h) { return __uint_as_float(((uint)h) << 16); }
__device__ inline ushort_t f2bf(float f) {
    uint u = __float_as_uint(f);
    u += 0x7fff + ((u >> 16) & 1);           // RNE
    return (ushort_t)(u >> 16);
}
// packed-f32 VOP3P ops (1 inst / 2 lanes). hipcc does not reliably form these
// from scalar float2 code -> explicit asm. Single-inst asm: output may alias
// inputs safely (read-then-write), no early-clobber needed.
__device__ inline f32x2v pk_add(f32x2v a, f32x2v b) {
    f32x2v d; asm("v_pk_add_f32 %0, %1, %2" : "=v"(d) : "v"(a), "v"(b)); return d;
}
__device__ inline f32x2v pk_fma(f32x2v a, f32x2v b, f32x2v c) {
    f32x2v d; asm("v_pk_fma_f32 %0, %1, %2, %3" : "=v"(d) : "v"(a), "v"(b), "v"(c)); return d;
}
__device__ inline f32x2v up2v(uint d) {      // 2 packed bf16 -> f32x2v, 2 inst
    f32x2v r; r.x = __uint_as_float(d << 16); r.y = __uint_as_float(d & 0xffff0000u); return r;
}
__device__ inline f32x2v pk_min0(f32x2v a) { // no v_pk_min_f32 -> 2 scalar mins
    f32x2v r; r.x = fminf(a.x, 0.f); r.y = fminf(a.y, 0.f); return r;
}

// ---------------------------------------------------------------------------
// prep (R6): dtype probe + deg zeroing + small-array canon + BOTH weight
// transposes. x canon moved to the hist dispatch (overlaps hist's atomic
// latency with canon's BW streaming - both depend only on this kernel).
// block roles: [0,NBZ) zero deg | [NBZ,NBZ+15) canon small4 | rest W transpose.
// ---------------------------------------------------------------------------
__global__ __launch_bounds__(256) void prep_kernel(
    const ushort_t* __restrict__ xprobe, int* flag,
    int* __restrict__ deg, int N, int NBZ,
    const void* a0, ushort_t* o0, int n0, const void* a1, ushort_t* o1, int n1,
    const void* a2, ushort_t* o2, int n2, const void* a3, ushort_t* o3, int n3,
    const void* __restrict__ Wl, const void* __restrict__ Wr,
    ushort_t* __restrict__ WtL, ushort_t* __restrict__ WtR, int Kk, int HCk) {
    __shared__ int s_isbf;
    __shared__ ushort_t t[64][72];
    int tid = threadIdx.x;
    if (tid < 64) {
        int hits = 0;
        for (int i = tid; i < 128; i += 64) {
            ushort_t w = xprobe[2 * i];
            uint hb = (w >> 8) & 0x7f;
            hits += (hb >= 0x38 && hb <= 0x42) ? 1 : 0;
        }
        #pragma unroll
        for (int off = 32; off >= 1; off >>= 1) hits += __shfl_xor(hits, off);
        if (tid == 0) s_isbf = (hits >= 64) ? 1 : 0;
    }
    __syncthreads();
    int isbf = s_isbf;
    int b = blockIdx.x;
    if (b == 0 && tid == 0) *flag = isbf;

    if (b < NBZ) {                       // zero deg (int4)
        int i0 = (b * 256 + tid) * 4;
        if (i0 + 4 <= N) *(int4*)&deg[i0] = make_int4(0, 0, 0, 0);
        else for (int j = 0; j < 4; ++j) if (i0 + j < N) deg[i0 + j] = 0;
        return;
    }
    if (b < NBZ + 15) {                  // canon small4
        int idx = (b - NBZ) * 256 + tid;
        const void* srcs[4] = {a0, a1, a2, a3};
        ushort_t* dsts[4] = {o0, o1, o2, o3};
        int ns[4] = {n0, n1, n2, n3};
        #pragma unroll
        for (int k = 0; k < 4; ++k) {
            if (idx < ns[k]) {
                dsts[k][idx] = isbf ? ((const ushort_t*)srcs[k])[idx]
                                    : f2bf(((const float*)srcs[k])[idx]);
                return;
            }
            idx -= ns[k];
        }
        return;
    }
    // W transpose+canon: out[HC][K] = in[K][HC]
    int b2 = b - (NBZ + 15);
    int z = b2 & 1;
    int rest = b2 >> 1;
    int ntk = Kk >> 6;                   // K/64 tiles
    int ky = rest % ntk, nxt = rest / ntk;
    const void* in = z ? Wr : Wl;
    ushort_t* outp = z ? WtR : WtL;
    int kt0 = ky * 64, nt0 = nxt * 64;
    int r = tid >> 3;                    // 0..31
    int c = (tid & 7) * 8;               // 0,8,..,56
    #pragma unroll
    for (int p = 0; p < 2; ++p) {
        int row = r + p * 32;
        size_t base = (size_t)(kt0 + row) * HCk + nt0 + c;
        if (isbf) {
            *(uint4*)&t[row][c] = *(const uint4*)((const ushort_t*)in + base);
        } else {
            const float* f = (const float*)in + base;
            float4 a = *(const float4*)f, bb = *(const float4*)(f + 4);
            ushort_t o[8] = {f2bf(a.x), f2bf(a.y), f2bf(a.z), f2bf(a.w),
                             f2bf(bb.x), f2bf(bb.y), f2bf(bb.z), f2bf(bb.w)};
            *(uint4*)&t[row][c] = *(uint4*)o;
        }
    }
    __syncthreads();
    #pragma unroll
    for (int p = 0; p < 2; ++p) {
        int row = r + p * 32;
        #pragma unroll
        for (int j = 0; j < 8; ++j)
            outp[(size_t)(nt0 + row) * Kk + kt0 + c + j] = t[c + j][row];
    }
}

// ---------------------------------------------------------------------------
// hist + x canon fused (independent roles, both depend only on prep):
// [0,NH) hist atomics | rest: x fp32->bf16 canon. Each block self-probes
// dtype (same 256B of x) so no cross-dispatch flag read needed.
// ---------------------------------------------------------------------------
__global__ __launch_bounds__(256) void histx_kernel(
    const ushort_t* __restrict__ xprobe,
    const int* __restrict__ dstE, int* deg, int E, int NH, int Ngr,
    const void* __restrict__ xin, ushort_t* __restrict__ xc, long long nx) {
    int tid = threadIdx.x;
    int b = blockIdx.x;
    if (b < NH) {                        // hist
        int i = b * 256 + tid;
        if (i < E) {
            int d = dstE[i];
            if ((uint)d < (uint)Ngr) atomicAdd(&deg[d], 1);
        }
        return;
    }
    __shared__ int s_isbf;
    if (tid < 64) {
        int hits = 0;
        for (int i = tid; i < 128; i += 64) {
            ushort_t w = xprobe[2 * i];
            uint hb = (w >> 8) & 0x7f;
            hits += (hb >= 0x38 && hb <= 0x42) ? 1 : 0;
        }
        #pragma unroll
        for (int off = 32; off >= 1; off >>= 1) hits += __shfl_xor(hits, off);
        if (tid == 0) s_isbf = (hits >= 64) ? 1 : 0;
    }
    __syncthreads();
    if (s_isbf) return;                  // x used directly when already bf16
    long long i0 = ((long long)(b - NH) * 256 + tid) * 8;
    if (i0 + 8 <= nx) {
        const float* f = (const float*)xin + i0;
        float4 a = *(const float4*)f, bb = *(const float4*)(f + 4);
        ushort_t o[8] = {f2bf(a.x), f2bf(a.y), f2bf(a.z), f2bf(a.w),
                         f2bf(bb.x), f2bf(bb.y), f2bf(bb.z), f2bf(bb.w)};
        *(uint4*)&xc[i0] = *(uint4*)o;
    } else {
        for (long long i = i0; i < nx; ++i) xc[i] = f2bf(((const float*)xin)[i]);
    }
}

// phase 1: per-1024-block exclusive scan over (deg[i] + 1)  [+1 = self-loop]
__global__ __launch_bounds__(256) void scan1(const int* __restrict__ deg, int* __restrict__ part,
                                             int* __restrict__ bsum, int N) {
    __shared__ int tmp[256];
    int b = blockIdx.x, tid = threadIdx.x;
    int i0 = b * 1024 + tid * 4;
    int v[4] = {0, 0, 0, 0};
    if (i0 + 4 <= N) { int4 q = *(const int4*)&deg[i0]; v[0]=q.x+1; v[1]=q.y+1; v[2]=q.z+1; v[3]=q.w+1; }
    else { for (int j = 0; j < 4; ++j) v[j] = (i0 + j < N) ? deg[i0 + j] + 1 : 0; }
    int s0 = v[0], s1 = s0 + v[1], s2 = s1 + v[2], s3 = s2 + v[3];
    tmp[tid] = s3;
    __syncthreads();
    for (int off = 1; off < 256; off <<= 1) {
        int t = (tid >= off) ? tmp[tid - off] : 0;
        __syncthreads();
        tmp[tid] += t;
        __syncthreads();
    }
    int base = tid ? tmp[tid - 1] : 0;
    int e[4] = {base, base + s0, base + s1, base + s2};
    if (i0 + 4 <= N) { *(int4*)&part[i0] = make_int4(e[0], e[1], e[2], e[3]); }
    else { for (int j = 0; j < 4; ++j) if (i0 + j < N) part[i0 + j] = e[j]; }
    if (tid == 255) bsum[b] = tmp[255];
}

// phase 2 (fused): each block wave-scans the Nb block sums itself (Nb <= 64)
__global__ __launch_bounds__(256) void scan3(const int* __restrict__ part, const int* __restrict__ bsum,
                                             int* __restrict__ offsets, int* __restrict__ cursor,
                                             int N, int Nb) {
    __shared__ int s_add, s_tot;
    int b = blockIdx.x, tid = threadIdx.x;
    if (tid < 64) {
        int v = (tid < Nb) ? bsum[tid] : 0;
        int incl = v;
        #pragma unroll
        for (int off = 1; off < 64; off <<= 1) {
            int t = __shfl_up(incl, off);
            if (tid >= off) incl += t;
        }
        if (tid == b) s_add = incl - v;
        if (tid == Nb - 1) s_tot = incl;
    }
    __syncthreads();
    int add = s_add;
    int i0 = b * 1024 + tid * 4;
    #pragma unroll
    for (int j = 0; j < 4; ++j) {
        int i = i0 + j;
        if (i < N) { int o = part[i] + add; offsets[i] = o; cursor[i] = o; }
    }
    if (b == Nb - 1 && tid == 0) offsets[N] = s_tot;   // = E + N
}

__global__ void scatter_kernel(const int* __restrict__ src, const int* __restrict__ dst,
                               int* cursor, int* srcs, int E, int N) {
    int i = blockIdx.x * blockDim.x + threadIdx.x;
    if (i >= E + N) return;
    int s, d;
    if (i < E) { s = src[i]; d = dst[i]; }
    else       { s = i - E; d = i - E; }   // self-loop
    if ((uint)d >= (uint)N) return;
    int pos = atomicAdd(&cursor[d], 1);
    if ((uint)pos < (uint)(E + N)) srcs[pos] = s;
}

// ---------------------------------------------------------------------------
// MFMA bf16 GEMM (R6: + fused scatter rows). C[M,N] = A[M,K] @ Bt[N,K]^T.
// 128x128 tile, 4 waves of 64x64, BK=64. Proven 114us on this shape.
// Grid rows [gyGemm, gridDim.y) run the CSR scatter instead (needs only
// scan3; overlaps its atomic-latency work under the GEMM). nScB guards.
// ---------------------------------------------------------------------------
__global__ __launch_bounds__(256) void gemm128(const ushort_t* A_bf, const ushort_t* A_cv,
                                               const int* __restrict__ flag,
                                               const ushort_t* __restrict__ Bt,
                                               ushort_t* __restrict__ C,
                                               int M, int Nn, int K, int gyGemm,
                                               const int* __restrict__ esrc,
                                               const int* __restrict__ edst,
                                               int* cursor, int* srcsOut,
                                               int E, int Ngr, int nScB) {
    if ((int)blockIdx.y >= gyGemm) {       // scatter role
        int id = ((int)blockIdx.y - gyGemm) * (int)gridDim.x + (int)blockIdx.x;
        if (id < nScB) {
            int i = id * 256 + (int)threadIdx.x;
            int EN = E + Ngr;
            if (i < EN) {
                int s, d;
                if (i < E) { s = esrc[i]; d = edst[i]; }
                else       { s = i - E; d = i - E; }   // self-loop
                if ((uint)d < (uint)Ngr) {
                    int pos = atomicAdd(&cursor[d], 1);
                    if ((uint)pos < (uint)EN) srcsOut[pos] = s;
                }
            }
        }
        return;
    }
    constexpr int CSTR = 132;                 // epilogue row stride (bank spread)
    __shared__ ushort_t SH[128 * CSTR];       // 33792 B; staging uses first 32KB
    ushort_t* As = SH;                        // As[2][4096]
    ushort_t* Bs = SH + 8192;                 // Bs[2][4096]
    const ushort_t* A = (*flag) ? A_bf : A_cv;
    int tid = threadIdx.x;
    int wave = tid >> 6, lane = tid & 63;
    int row0 = blockIdx.y * 128, col0 = blockIdx.x * 128;
    int wm = (wave >> 1) * 64, wn = (wave & 1) * 64;

    f32x4v acc[4][4];
    #pragma unroll
    for (int i = 0; i < 4; ++i)
        #pragma unroll
        for (int j = 0; j < 4; ++j) acc[i][j] = (f32x4v){0.f, 0.f, 0.f, 0.f};

    int fm = lane & 15, kq8 = (lane >> 4) * 8;

    // staging (r6 mapping, coalesced 64B runs): chunk p -> row=p>>2, kp=p&3
    const ushort_t* srcA[2]; ushort_t* dstA0[2]; ushort_t* dstA1[2];
    const ushort_t* srcB[2]; ushort_t* dstB0[2]; ushort_t* dstB1[2];
    #pragma unroll
    for (int i = 0; i < 2; ++i) {
        int p = (wave * 2 + i) * 64 + lane;
        int row = p >> 2, kp = p & 3;
        int gra = row0 + row; if (gra >= M) gra = M - 1;   // tail clamp (C-write guarded)
        srcA[i] = &A[(size_t)gra * K + kp * 8];
        srcB[i] = &Bt[(size_t)(col0 + row) * K + kp * 8];
        dstA0[i] = &As[p * 8]; dstA1[i] = &As[4096 + p * 8];
        dstB0[i] = &Bs[p * 8]; dstB1[i] = &Bs[4096 + p * 8];
    }

    for (int k0 = 0; k0 < K; k0 += 64) {
        #pragma unroll
        for (int i = 0; i < 2; ++i) {
            __builtin_amdgcn_global_load_lds((g_u32_t*)srcA[i],        (lds_u32_t*)dstA0[i], 16, 0, 0);
            __builtin_amdgcn_global_load_lds((g_u32_t*)(srcA[i] + 32), (lds_u32_t*)dstA1[i], 16, 0, 0);
            __builtin_amdgcn_global_load_lds((g_u32_t*)srcB[i],        (lds_u32_t*)dstB0[i], 16, 0, 0);
            __builtin_amdgcn_global_load_lds((g_u32_t*)(srcB[i] + 32), (lds_u32_t*)dstB1[i], 16, 0, 0);
            srcA[i] += 64; srcB[i] += 64;
        }
        __syncthreads();

        #pragma unroll
        for (int panel = 0; panel < 2; ++panel) {
            bf16x8v af[4], bfr[4];
            #pragma unroll
            for (int mi = 0; mi < 4; ++mi)
                af[mi] = *(const bf16x8v*)&As[panel * 4096 + (wm + mi * 16 + fm) * 32 + kq8];
            #pragma unroll
            for (int nj = 0; nj < 4; ++nj)
                bfr[nj] = *(const bf16x8v*)&Bs[panel * 4096 + (wn + nj * 16 + fm) * 32 + kq8];
            #pragma unroll
            for (int mi = 0; mi < 4; ++mi)
                #pragma unroll
                for (int nj = 0; nj < 4; ++nj)
                    acc[mi][nj] = __builtin_amdgcn_mfma_f32_16x16x32_bf16(af[mi], bfr[nj], acc[mi][nj], 0, 0, 0);
        }
        __syncthreads();
    }

    // epilogue: C/D layout col = lane&15, row = (lane>>4)*4 + r  [verified r4-r14]
    int col = lane & 15, rq = (lane >> 4) * 4;
    #pragma unroll
    for (int mi = 0; mi < 4; ++mi)
        #pragma unroll
        for (int r = 0; r < 4; ++r)
            #pragma unroll
            for (int nj = 0; nj < 4; ++nj)
                SH[(wm + mi * 16 + rq + r) * CSTR + wn + nj * 16 + col] = f2bf(acc[mi][nj][r]);
    __syncthreads();
    #pragma unroll
    for (int j = 0; j < 8; ++j) {
        int base = (tid + j * 256) * 8;        // idx in 128x128 space
        int r = base >> 7, c = base & 127;
        int gm = row0 + r;
        if (gm < M)
            *(uint4*)&C[(size_t)gm * Nn + col0 + c] = *(const uint4*)&SH[r * CSTR + c];
    }
}

// ---------------------------------------------------------------------------
// gat (R6): R5 structure + explicit v_pk_{add,fma}_f32 for the channel math.
// Per-edge per-wave VALU: 8 groups x {unpack 2, pk_add 1, min 2, pk_fma 3}
// = 66 inst vs 96 scalar (-24% total; kernel was 77% VALUBusy). Layout
// unchanged: 2 waves/node, wave w -> heads 2w,2w+1, 16 ch/lane, butterfly
// within 32-lane halves, 2-edge-pair prefetch, nt xr loads. OUTPUT FP32.
// ---------------------------------------------------------------------------
__global__ __launch_bounds__(128, 4) void gat_aggregate(
    const ushort_t* __restrict__ xl, int xl_stride,
    const ushort_t* __restrict__ xr, int xr_stride,
    const int* __restrict__ offsets, const int* __restrict__ srcs,
    const ushort_t* __restrict__ att, const ushort_t* __restrict__ bias,
    const ushort_t* __restrict__ Wc, const ushort_t* __restrict__ bc,
    float* __restrict__ out, int c0, int Cn, int N, int EN) {
    int bn = blockIdx.x;
    if (bn >= Cn) return;
    int n = c0 + bn;
    int tid = threadIdx.x;
    int w = tid >> 6, lane = tid & 63;
    int h = 2 * w + (lane >> 5);             // this lane's head
    int r = lane & 31;                       // 32 lanes per head
    int hoff = h * FEAT + r * 16;            // 16 channels per lane

    __shared__ float sh[HEADS][FEAT];
    __shared__ float r0s[2], r1s[2];

    f32x2v xrr[8], attr[8];
    { const uint4v* p = (const uint4v*)&xr[(size_t)bn * xr_stride + hoff];
      uint4v qa = __builtin_nontemporal_load(p);          // xr read exactly once
      uint4v qb = __builtin_nontemporal_load(p + 1);
      xrr[0] = up2v(qa.x); xrr[1] = up2v(qa.y); xrr[2] = up2v(qa.z); xrr[3] = up2v(qa.w);
      xrr[4] = up2v(qb.x); xrr[5] = up2v(qb.y); xrr[6] = up2v(qb.z); xrr[7] = up2v(qb.w); }
    { const ushort_t* p = &att[hoff];
      uint4 qa = *(const uint4*)p, qb = *(const uint4*)(p + 8);
      attr[0] = up2v(qa.x); attr[1] = up2v(qa.y); attr[2] = up2v(qa.z); attr[3] = up2v(qa.w);
      attr[4] = up2v(qb.x); attr[5] = up2v(qb.y); attr[6] = up2v(qb.z); attr[7] = up2v(qb.w); }

    int start = offsets[n], end = offsets[n + 1];
    start = max(0, min(start, EN));
    end   = max(start, min(end, EN));
    int deg = end - start;

    int sv = 0;
    if (lane < deg) sv = srcs[start + lane];

    float l = 0.f;
    f32x2v acc[8] = {{0.f,0.f},{0.f,0.f},{0.f,0.f},{0.f,0.f},
                     {0.f,0.f},{0.f,0.f},{0.f,0.f},{0.f,0.f}};
    const ushort_t* xlh = xl + hoff;
    const f32x2v cneg = {NEG - 1.0f, NEG - 1.0f};

    auto getS = [&](int i) -> int {
        if (i >= deg) i = deg - 1;
        if (i < 0) i = 0;
        int s = (i < 64) ? __shfl(sv, i) : srcs[start + i];
        return ((uint)s >= (uint)N) ? 0 : s;
    };
    auto fetchE = [&](int i, uint4& qa, uint4& qb) {
        int s = getS(i);
        const ushort_t* pp = xlh + (size_t)s * xl_stride;
        qa = *(const uint4*)pp;
        qb = *(const uint4*)(pp + 8);
    };
    auto body = [&](uint4 qa, uint4 qb) {
        f32x2v v[8] = {up2v(qa.x), up2v(qa.y), up2v(qa.z), up2v(qa.w),
                       up2v(qb.x), up2v(qb.y), up2v(qb.z), up2v(qb.w)};
        f32x2v p2 = {0.f, 0.f};
        #pragma unroll
        for (int j = 0; j < 8; ++j) {
            f32x2v u  = pk_add(v[j], xrr[j]);
            f32x2v lr = pk_fma(pk_min0(u), cneg, u);   // packed LeakyReLU
            p2 = pk_fma(lr, attr[j], p2);
        }
        float p = p2.x + p2.y;
        #pragma unroll
        for (int off = 16; off >= 1; off >>= 1) p += __shfl_xor(p, off);  // intra-half
        float wgt = __expf(p);
        l += wgt;
        f32x2v wv; wv.x = wgt; wv.y = wgt;
        #pragma unroll
        for (int j = 0; j < 8; ++j) acc[j] = pk_fma(wv, v[j], acc[j]);
    };

    uint4 a0q, a0r, a1q, a1r, b0q, b0r, b1q, b1r;
    fetchE(0, a0q, a0r);
    fetchE(1, a1q, a1r);
    for (int e = 0; e < deg; e += 2) {
        fetchE(e + 2, b0q, b0r);     // clamped on tail -> L1 hit, discarded
        fetchE(e + 3, b1q, b1r);
        body(a0q, a0r);
        if (e + 1 < deg) body(a1q, a1r);
        a0q = b0q; a0r = b0r; a1q = b1q; a1r = b1r;
    }

    float inv = 0.25f / fmaxf(l, 1e-35f);   // 1/l, mean over heads folded in
    #pragma unroll
    for (int j = 0; j < 8; ++j) {
        sh[h][r * 16 + 2 * j]     = acc[j].x * inv;
        sh[h][r * 16 + 2 * j + 1] = acc[j].y * inv;
    }
    __syncthreads();

    float p0 = 0.f, p1 = 0.f;
    #pragma unroll
    for (int c = tid; c < FEAT; c += 128) {
        float f = sh[0][c] + sh[1][c] + sh[2][c] + sh[3][c] + bf2f(bias[c]);
        uint w2 = *(const uint*)&Wc[c * 2];
        p0 = fmaf(f, bf2f((ushort_t)(w2 & 0xffff)), p0);
        p1 = fmaf(f, bf2f((ushort_t)(w2 >> 16)), p1);
    }
    #pragma unroll
    for (int off = 32; off >= 1; off >>= 1) {
        p0 += __shfl_xor(p0, off);
        p1 += __shfl_xor(p1, off);
    }
    if (lane == 0) { r0s[w] = p0; r1s[w] = p1; }
    __syncthreads();
    if (tid == 0) {
        out[(size_t)n * 2 + 0] = r0s[0] + r0s[1] + bf2f(bc[0]);
        out[(size_t)n * 2 + 1] = r1s[0] + r1s[1] + bf2f(bc[1]);
    }
}

// ---------------------------------------------------------------------------
extern "C" void kernel_launch(void* const* d_in, const int* in_sizes, int n_in,
                              void* d_out, int out_size, void* d_ws, size_t ws_size,
                              hipStream_t stream) {
    const void* x    = d_in[0];
    const int*  ei   = (const int*)d_in[1];
    const void* W_l  = d_in[2];
    const void* W_r  = d_in[3];
    const void* att  = d_in[4];
    const void* bias = d_in[5];
    const void* Wc   = d_in[6];
    const void* bc   = d_in[7];
    float* out = (float*)d_out;

    const int N  = in_sizes[0] / FEAT;     // 20000
    const int E  = in_sizes[1] / 2;        // 160000
    const int K  = FEAT;                   // 512
    const int HC = HEADS * FEAT;           // 2048
    const int EN = E + N;
    const int Nb = (N + 1023) / 1024;      // scan blocks (20 <= 64)

    const int* src = ei;
    const int* dst = ei + E;

    // ---- adaptive workspace layout ----
    char* base = (char*)d_ws;
    size_t off = 0;
    auto alloc = [&](size_t bytes) -> char* {
        char* p = base + off;
        off = (off + bytes + 255) & ~(size_t)255;
        return p;
    };
    int* flag    = (int*)alloc(4);
    int* offsets = (int*)alloc((size_t)(N + 1) * 4);
    int* cursor  = (int*)alloc((size_t)N * 4);
    int* deg     = (int*)alloc((size_t)N * 4);
    int* part    = (int*)alloc((size_t)N * 4);
    int* bsum    = (int*)alloc((size_t)(Nb + 1) * 4);
    int* srcs    = (int*)alloc((size_t)EN * 4);
    ushort_t* attc  = (ushort_t*)alloc((size_t)HC * 2);
    ushort_t* biasc = (ushort_t*)alloc((size_t)FEAT * 2);
    ushort_t* Wcc   = (ushort_t*)alloc((size_t)FEAT * 2 * 2);
    ushort_t* bcc   = (ushort_t*)alloc(2 * 2);
    ushort_t* xc   = (ushort_t*)alloc((size_t)N * K * 2);
    ushort_t* Wcat = (ushort_t*)alloc((size_t)2 * HC * K * 2);   // [Wl^T ; Wr^T]
    size_t fixed = off;

    size_t need_merged = (size_t)N * 2 * HC * 2;
    bool merged = (ws_size >= fixed + need_merged);

    // 0) prep: probe + deg-zero + small canon + W transpose
    long long NX = (long long)N * K;
    const int NBZ = (N + 1023) / 1024;                       // deg-zero blocks
    const int nT = (HC / 64) * (K / 64) * 2;                 // 512 transpose blocks
    prep_kernel<<<NBZ + 15 + nT, 256, 0, stream>>>(
        (const ushort_t*)x, flag, deg, N, NBZ,
        att, attc, HC, bias, biasc, FEAT, Wc, Wcc, FEAT * 2, bc, bcc, 2,
        W_l, W_r, Wcat, Wcat + (size_t)HC * K, K, HC);

    // 1) hist + x canon fused (both depend only on prep)
    const int NH = (E + 255) / 256;
    int nxb = (int)((NX / 8 + 255) / 256);
    histx_kernel<<<NH + nxb, 256, 0, stream>>>(
        (const ushort_t*)x, dst, deg, E, NH, N, x, xc, NX);

    // 2) scans
    scan1<<<Nb, 256, 0, stream>>>(deg, part, bsum, N);
    scan3<<<Nb, 256, 0, stream>>>(part, bsum, offsets, cursor, N, Nb);

    const ushort_t* x_bf = (const ushort_t*)x;
    const int nScB = (EN + 255) / 256;                       // scatter blocks

    if (merged) {
        ushort_t* xlr = (ushort_t*)(base + fixed);       // N x 4096: [xl | xr]
        int gx = 2 * HC / 128;                           // 32
        int gyG = (N + 127) / 128;                       // 157
        int exR = (nScB + gx - 1) / gx;                  // 22 scatter rows
        dim3 gg(gx, gyG + exR);
        // 3) gemm + fused scatter (scatter needs only scan3; overlaps gemm)
        gemm128<<<gg, 256, 0, stream>>>(x_bf, xc, flag, Wcat, xlr, N, 2 * HC, K,
                                        gyG, src, dst, cursor, srcs, E, N, nScB);
        // 4) gat
        gat_aggregate<<<N, 128, 0, stream>>>(xlr, 2 * HC, xlr + HC, 2 * HC,
                                             offsets, srcs, attc, biasc, Wcc, bcc,
                                             out, 0, N, N, EN);
    } else {
        // fallback: separate scatter + xl + chunked xr
        scatter_kernel<<<nScB, 256, 0, stream>>>(src, dst, cursor, srcs, E, N);
        ushort_t* xl = (ushort_t*)alloc((size_t)N * HC * 2);
        size_t remain = (ws_size > off) ? (ws_size - off) : 0;
        long long Cmax = (long long)(remain / ((size_t)HC * 2));
        int C = (Cmax >= N) ? N : (int)(Cmax & ~63LL);
        if (C < 64) C = 64;
        ushort_t* xrc = (ushort_t*)(base + off);
        ushort_t* Wlt = Wcat;
        ushort_t* Wrt = Wcat + (size_t)HC * K;

        dim3 gl(HC / 128, (N + 127) / 128);
        gemm128<<<gl, 256, 0, stream>>>(x_bf, xc, flag, Wlt, xl, N, HC, K,
                                        (N + 127) / 128, nullptr, nullptr,
                                        nullptr, nullptr, 0, 0, 0);
        for (int c0 = 0; c0 < N; c0 += C) {
            int Cn = (N - c0 < C) ? (N - c0) : C;
            dim3 gr(HC / 128, (Cn + 127) / 128);
            gemm128<<<gr, 256, 0, stream>>>(x_bf + (size_t)c0 * K, xc + (size_t)c0 * K, flag,
                                            Wrt, xrc, Cn, HC, K,
                                            (Cn + 127) / 128, nullptr, nullptr,
                                            nullptr, nullptr, 0, 0, 0);
            gat_aggregate<<<Cn, 128, 0, stream>>>(xl, HC, xrc, HC,
                                                  offsets, srcs, attc, biasc, Wcc, bcc,
                                                  out, c0, Cn, N, EN);
        }
    }
}